// Round 2
// baseline (442.214 us; speedup 1.0000x reference)
//
#include <hip/hip_runtime.h>
#include <hip/hip_bf16.h>

// GAT layer: N=50000 nodes, E=1.6M edges, IN=128, OUT=32, HEADS=4 (H*O=128)
// Pipeline:
//   1. k_gemm:   z[n][c] = dot(h[n,:], Wc[c,:])       (c = h*32+o)
//   2. k_scores: s_src[n][h], s_dst[n][h] from z and a
//   3. k_hist:   deg[dst]++ histogram
//   4. k_starts: wave-aggregated atomic allocation of contiguous per-node slots
//   5. k_fill:   scatter src ids into dst-grouped edge list (CSR)
//   6. k_gat:    per-node softmax + weighted gather-accumulate (1 wave/node)
// (Resubmission of round-0 kernel: previous bench died on container acquisition,
//  not on the kernel.)

#define NN 50000
#define NE 1600000
#define IN_DIM 128
#define OC 128

__device__ __forceinline__ float lrelu(float x) { return x >= 0.f ? x : 0.01f * x; }

__device__ __forceinline__ float readlane_f(float v, int l) {
    return __builtin_bit_cast(float, __builtin_amdgcn_readlane(__builtin_bit_cast(int, v), l));
}

// ---------------------------------------------------------------- projection
// z = h @ Wc^T.  Tile: 64 nodes x 128 ch, k-tiles of 64. LDS transposed+padded.
__global__ __launch_bounds__(256) void k_gemm(const float* __restrict__ h,
                                              const float* __restrict__ W,
                                              float* __restrict__ z) {
    __shared__ float hs[64][65];    // [k][node]
    __shared__ float ws[64][129];   // [k][channel]
    const int t  = threadIdx.x;
    const int n0 = blockIdx.x * 64;
    const int tx = t & 31;   // channel base: c = tx + 32*j
    const int ty = t >> 5;   // node base:    n = ty + 8*i

    float acc[8][4];
#pragma unroll
    for (int i = 0; i < 8; ++i)
#pragma unroll
        for (int j = 0; j < 4; ++j) acc[i][j] = 0.f;

    for (int kt = 0; kt < IN_DIM; kt += 64) {
        // load h tile: 64 nodes x 64 k = 1024 float4
#pragma unroll
        for (int s = 0; s < 4; ++s) {
            const int idx4 = t + s * 256;
            const int n    = idx4 >> 4;
            const int kk   = (idx4 & 15) << 2;
            const int gn   = n0 + n;
            float4 v = make_float4(0.f, 0.f, 0.f, 0.f);
            if (gn < NN) v = *(const float4*)(h + (size_t)gn * IN_DIM + kt + kk);
            hs[kk + 0][n] = v.x; hs[kk + 1][n] = v.y;
            hs[kk + 2][n] = v.z; hs[kk + 3][n] = v.w;
        }
        // load W tile: 128 ch x 64 k = 2048 float4
#pragma unroll
        for (int s = 0; s < 8; ++s) {
            const int idx4 = t + s * 256;
            const int c    = idx4 >> 4;
            const int kk   = (idx4 & 15) << 2;
            const float4 v = *(const float4*)(W + (size_t)c * IN_DIM + kt + kk);
            ws[kk + 0][c] = v.x; ws[kk + 1][c] = v.y;
            ws[kk + 2][c] = v.z; ws[kk + 3][c] = v.w;
        }
        __syncthreads();
#pragma unroll 4
        for (int k = 0; k < 64; ++k) {
            float wv[4], hv[8];
#pragma unroll
            for (int j = 0; j < 4; ++j) wv[j] = ws[k][tx + 32 * j];
#pragma unroll
            for (int i = 0; i < 8; ++i) hv[i] = hs[k][ty + 8 * i];
#pragma unroll
            for (int i = 0; i < 8; ++i)
#pragma unroll
                for (int j = 0; j < 4; ++j) acc[i][j] = fmaf(hv[i], wv[j], acc[i][j]);
        }
        __syncthreads();
    }
#pragma unroll
    for (int i = 0; i < 8; ++i) {
        const int gn = n0 + ty + 8 * i;
        if (gn < NN) {
#pragma unroll
            for (int j = 0; j < 4; ++j) z[(size_t)gn * OC + tx + 32 * j] = acc[i][j];
        }
    }
}

// ------------------------------------------------------------- score tables
__global__ __launch_bounds__(256) void k_scores(const float* __restrict__ z,
                                                const float* __restrict__ a,
                                                float* __restrict__ ssrc,
                                                float* __restrict__ sdst) {
    const int u = blockIdx.x * 256 + threadIdx.x;
    if (u >= NN * 4) return;
    const int n  = u >> 2;
    const int hh = u & 3;
    const float* zp = z + (size_t)n * OC + hh * 32;
    const float* as = a + hh * 64;
    float accs = 0.f, accd = 0.f;
#pragma unroll
    for (int i = 0; i < 32; i += 4) {
        const float4 zv = *(const float4*)(zp + i);
        const float4 av = *(const float4*)(as + i);
        const float4 bv = *(const float4*)(as + 32 + i);
        accs += zv.x * av.x + zv.y * av.y + zv.z * av.z + zv.w * av.w;
        accd += zv.x * bv.x + zv.y * bv.y + zv.z * bv.z + zv.w * bv.w;
    }
    ssrc[u] = accs;
    sdst[u] = accd;
}

// ------------------------------------------------------------------- CSR build
__global__ __launch_bounds__(256) void k_hist(const int* __restrict__ dst,
                                              int* __restrict__ deg) {
    const int e = blockIdx.x * 256 + threadIdx.x;
    if (e < NE) atomicAdd(&deg[dst[e]], 1);
}

__global__ __launch_bounds__(256) void k_starts(const int* __restrict__ deg,
                                                int* __restrict__ counter,
                                                int* __restrict__ startv,
                                                int* __restrict__ cursor) {
    const int n    = blockIdx.x * 256 + threadIdx.x;
    const int lane = threadIdx.x & 63;
    const int d    = (n < NN) ? deg[n] : 0;
    int v = d;
#pragma unroll
    for (int off = 1; off < 64; off <<= 1) {
        const int u = __shfl_up(v, off);
        if (lane >= off) v += u;
    }
    const int excl  = v - d;
    const int total = __shfl(v, 63);
    int base = 0;
    if (lane == 63) base = atomicAdd(counter, total);
    base = __shfl(base, 63);
    if (n < NN) {
        const int s = base + excl;
        startv[n] = s;
        cursor[n] = s;
    }
}

__global__ __launch_bounds__(256) void k_fill(const int* __restrict__ src,
                                              const int* __restrict__ dst,
                                              int* __restrict__ cursor,
                                              int* __restrict__ esrc) {
    const int e = blockIdx.x * 256 + threadIdx.x;
    if (e < NE) {
        const int d   = dst[e];
        const int pos = atomicAdd(&cursor[d], 1);
        esrc[pos] = src[e];
    }
}

// --------------------------------------------------------------- main per-node
// 1 wave per dst node; lane owns channels (lane) and (lane+64).
// head of channel c is c>>5:  lane<32 -> heads {0,2}, lane>=32 -> heads {1,3}.
__global__ __launch_bounds__(256) void k_gat(const float* __restrict__ z,
                                             const float* __restrict__ ssrc,
                                             const float* __restrict__ sdst,
                                             const int* __restrict__ startv,
                                             const int* __restrict__ deg,
                                             const int* __restrict__ esrc,
                                             float* __restrict__ out) {
    const int node = blockIdx.x * 4 + threadIdx.y;
    const int lane = threadIdx.x;
    const int s0   = startv[node];
    const int d    = deg[node];
    const float4 sd = ((const float4*)sdst)[node];

    // pass A: per-head max (lane-parallel over edges)
    float m0 = -1e30f, m1 = -1e30f, m2 = -1e30f, m3 = -1e30f;
    for (int j = lane; j < d; j += 64) {
        const int sid   = esrc[s0 + j];
        const float4 ss = ((const float4*)ssrc)[sid];
        m0 = fmaxf(m0, lrelu(ss.x + sd.x));
        m1 = fmaxf(m1, lrelu(ss.y + sd.y));
        m2 = fmaxf(m2, lrelu(ss.z + sd.z));
        m3 = fmaxf(m3, lrelu(ss.w + sd.w));
    }
#pragma unroll
    for (int off = 32; off > 0; off >>= 1) {
        m0 = fmaxf(m0, __shfl_xor(m0, off));
        m1 = fmaxf(m1, __shfl_xor(m1, off));
        m2 = fmaxf(m2, __shfl_xor(m2, off));
        m3 = fmaxf(m3, __shfl_xor(m3, off));
    }

    // pass B: chunk-preload exp weights per owning lane, then serial broadcast
    float acc0 = 0.f, acc1 = 0.f;
    float dn0 = 0.f, dn1 = 0.f, dn2 = 0.f, dn3 = 0.f;
    for (int base = 0; base < d; base += 64) {
        const int myj = base + lane;
        int   sid_l = 0;
        float x0 = 0.f, x1 = 0.f, x2 = 0.f, x3 = 0.f;
        if (myj < d) {
            sid_l = esrc[s0 + myj];
            const float4 ss = ((const float4*)ssrc)[sid_l];
            x0 = __expf(lrelu(ss.x + sd.x) - m0);
            x1 = __expf(lrelu(ss.y + sd.y) - m1);
            x2 = __expf(lrelu(ss.z + sd.z) - m2);
            x3 = __expf(lrelu(ss.w + sd.w) - m3);
            dn0 += x0; dn1 += x1; dn2 += x2; dn3 += x3;
        }
        const int cnt = min(64, d - base);
#pragma unroll 4
        for (int j = 0; j < cnt; ++j) {
            const int   sid = __builtin_amdgcn_readlane(sid_l, j);
            const float e0  = readlane_f(x0, j);
            const float e1  = readlane_f(x1, j);
            const float e2  = readlane_f(x2, j);
            const float e3  = readlane_f(x3, j);
            const float xa  = (lane < 32) ? e0 : e1;
            const float xb  = (lane < 32) ? e2 : e3;
            const float* zp = z + (size_t)sid * OC;
            acc0 = fmaf(xa, zp[lane], acc0);
            acc1 = fmaf(xb, zp[64 + lane], acc1);
        }
    }
#pragma unroll
    for (int off = 32; off > 0; off >>= 1) {
        dn0 += __shfl_xor(dn0, off);
        dn1 += __shfl_xor(dn1, off);
        dn2 += __shfl_xor(dn2, off);
        dn3 += __shfl_xor(dn3, off);
    }
    const float da = (lane < 32) ? dn0 : dn1;
    const float db = (lane < 32) ? dn2 : dn3;
    out[(size_t)node * OC + lane]      = (da > 0.f) ? acc0 / da : 0.f;
    out[(size_t)node * OC + 64 + lane] = (db > 0.f) ? acc1 / db : 0.f;
}

// ------------------------------------------------------------------- launcher
extern "C" void kernel_launch(void* const* d_in, const int* in_sizes, int n_in,
                              void* d_out, int out_size, void* d_ws, size_t ws_size,
                              hipStream_t stream) {
    const float* h_in = (const float*)d_in[0];
    const float* W    = (const float*)d_in[1];
    const float* a    = (const float*)d_in[2];
    const int*   src  = (const int*)d_in[3];
    const int*   dst  = (const int*)d_in[4];
    float*       out  = (float*)d_out;

    char* w = (char*)d_ws;
    float* z       = (float*)(w);                    // 25,600,000 B
    float* ssrc    = (float*)(w + 25600000);         //    800,000 B
    float* sdst    = (float*)(w + 26400000);         //    800,000 B
    int*   deg     = (int*)(w + 27200000);           //    200,000 B
    int*   counter = (int*)(w + 27400000);           //        256 B
    int*   startv  = (int*)(w + 27400256);           //    200,000 B
    int*   cursor  = (int*)(w + 27600256);           //    200,000 B
    int*   esrc    = (int*)(w + 27800256);           //  6,400,000 B
    // total: 34,200,256 B

    // zero deg + counter (contiguous region)
    hipMemsetAsync(w + 27200000, 0, 200256, stream);

    k_gemm  <<<(NN + 63) / 64, 256, 0, stream>>>(h_in, W, z);
    k_scores<<<(NN * 4 + 255) / 256, 256, 0, stream>>>(z, a, ssrc, sdst);
    k_hist  <<<(NE + 255) / 256, 256, 0, stream>>>(dst, deg);
    k_starts<<<(NN + 255) / 256, 256, 0, stream>>>(deg, counter, startv, cursor);
    k_fill  <<<(NE + 255) / 256, 256, 0, stream>>>(src, dst, cursor, esrc);
    k_gat   <<<NN / 4, dim3(64, 4), 0, stream>>>(z, ssrc, sdst, startv, deg, esrc, out);
}

// Round 3
// 418.344 us; speedup vs baseline: 1.0571x; 1.0571x over previous
//
#include <hip/hip_runtime.h>
#include <hip/hip_bf16.h>
#include <stdint.h>

// GAT layer: N=50000, E=1.6M, IN=128, OUT=32, H=4 (H*O=128)
// v2: bf16 z gathers (halve L2-miss bytes), no-max softmax (exp range safe),
//     binned CSR build (kill partial-line scatter writes), ushort esrc.

#define NN 50000
#define NE 1600000
#define IN_DIM 128
#define OC 128
#define NBSH 6
#define NBUCK ((NN + 63) >> 6)   // 782 buckets of 64 dst nodes
#define CURS 16                  // bucket cursor stride (ints) = 64 B padding

__device__ __forceinline__ float lrelu(float x) { return x >= 0.f ? x : 0.01f * x; }

// ---------------------------------------------------------------- projection
// z_bf16 = bf16(h @ Wc^T).  64 nodes x 128 ch tile, k-tiles of 64.
__global__ __launch_bounds__(256) void k_gemm(const float* __restrict__ h,
                                              const float* __restrict__ W,
                                              __hip_bfloat16* __restrict__ zb) {
    __shared__ float hs[64][65];    // [k][node]
    __shared__ float ws[64][129];   // [k][channel]
    const int t  = threadIdx.x;
    const int n0 = blockIdx.x * 64;
    const int tx = t & 31;   // channel base: c = tx + 32*j
    const int ty = t >> 5;   // node base:    n = ty + 8*i

    float acc[8][4];
#pragma unroll
    for (int i = 0; i < 8; ++i)
#pragma unroll
        for (int j = 0; j < 4; ++j) acc[i][j] = 0.f;

    for (int kt = 0; kt < IN_DIM; kt += 64) {
#pragma unroll
        for (int s = 0; s < 4; ++s) {
            const int idx4 = t + s * 256;
            const int n    = idx4 >> 4;
            const int kk   = (idx4 & 15) << 2;
            const int gn   = n0 + n;
            float4 v = make_float4(0.f, 0.f, 0.f, 0.f);
            if (gn < NN) v = *(const float4*)(h + (size_t)gn * IN_DIM + kt + kk);
            hs[kk + 0][n] = v.x; hs[kk + 1][n] = v.y;
            hs[kk + 2][n] = v.z; hs[kk + 3][n] = v.w;
        }
#pragma unroll
        for (int s = 0; s < 8; ++s) {
            const int idx4 = t + s * 256;
            const int c    = idx4 >> 4;
            const int kk   = (idx4 & 15) << 2;
            const float4 v = *(const float4*)(W + (size_t)c * IN_DIM + kt + kk);
            ws[kk + 0][c] = v.x; ws[kk + 1][c] = v.y;
            ws[kk + 2][c] = v.z; ws[kk + 3][c] = v.w;
        }
        __syncthreads();
#pragma unroll 4
        for (int k = 0; k < 64; ++k) {
            float wv[4], hv[8];
#pragma unroll
            for (int j = 0; j < 4; ++j) wv[j] = ws[k][tx + 32 * j];
#pragma unroll
            for (int i = 0; i < 8; ++i) hv[i] = hs[k][ty + 8 * i];
#pragma unroll
            for (int i = 0; i < 8; ++i)
#pragma unroll
                for (int j = 0; j < 4; ++j) acc[i][j] = fmaf(hv[i], wv[j], acc[i][j]);
        }
        __syncthreads();
    }
#pragma unroll
    for (int i = 0; i < 8; ++i) {
        const int gn = n0 + ty + 8 * i;
        if (gn < NN) {
#pragma unroll
            for (int j = 0; j < 4; ++j)
                zb[(size_t)gn * OC + tx + 32 * j] = __float2bfloat16(acc[i][j]);
        }
    }
}

// ------------------------------------------------------------- score tables
// s_src[n][h], s_dst[n][h] from bf16 z.
__global__ __launch_bounds__(256) void k_scores(const uint32_t* __restrict__ zb32,
                                                const float* __restrict__ a,
                                                float* __restrict__ ssrc,
                                                float* __restrict__ sdst) {
    const int u = blockIdx.x * 256 + threadIdx.x;
    if (u >= NN * 4) return;
    const int n  = u >> 2;
    const int hh = u & 3;
    const uint4* zp = (const uint4*)(zb32 + (size_t)n * 64 + hh * 16);
    const float4* as = (const float4*)(a + hh * 64);        // src weights: 8 float4
    const float4* ad = as + 8;                               // dst weights
    float accs = 0.f, accd = 0.f;
#pragma unroll
    for (int k4 = 0; k4 < 4; ++k4) {
        const uint4 U = zp[k4];
        const float4 a0 = as[2 * k4], a1 = as[2 * k4 + 1];
        const float4 b0 = ad[2 * k4], b1 = ad[2 * k4 + 1];
        float zf[8];
        zf[0] = __builtin_bit_cast(float, U.x << 16);
        zf[1] = __builtin_bit_cast(float, U.x & 0xffff0000u);
        zf[2] = __builtin_bit_cast(float, U.y << 16);
        zf[3] = __builtin_bit_cast(float, U.y & 0xffff0000u);
        zf[4] = __builtin_bit_cast(float, U.z << 16);
        zf[5] = __builtin_bit_cast(float, U.z & 0xffff0000u);
        zf[6] = __builtin_bit_cast(float, U.w << 16);
        zf[7] = __builtin_bit_cast(float, U.w & 0xffff0000u);
        accs += zf[0]*a0.x + zf[1]*a0.y + zf[2]*a0.z + zf[3]*a0.w
              + zf[4]*a1.x + zf[5]*a1.y + zf[6]*a1.z + zf[7]*a1.w;
        accd += zf[0]*b0.x + zf[1]*b0.y + zf[2]*b0.z + zf[3]*b0.w
              + zf[4]*b1.x + zf[5]*b1.y + zf[6]*b1.z + zf[7]*b1.w;
    }
    ssrc[u] = accs;
    sdst[u] = accd;
}

// ------------------------------------------------------------------- CSR build
__global__ __launch_bounds__(256) void k_hist(const int* __restrict__ dst,
                                              int* __restrict__ deg) {
    const int e = blockIdx.x * 256 + threadIdx.x;
    if (e < NE) atomicAdd(&deg[dst[e]], 1);
}

// single block: bucket sums from deg + exclusive scan -> bucket_base, cursors
__global__ __launch_bounds__(1024) void k_bscan(const int* __restrict__ deg,
                                                int* __restrict__ bucket_base,
                                                int* __restrict__ bucket_cursor) {
    __shared__ int s[1024];
    const int t = threadIdx.x;
    int sum = 0;
    if (t < NBUCK) {
        const int n0 = t << NBSH;
#pragma unroll 4
        for (int i = 0; i < 64; ++i) {
            const int n = n0 + i;
            if (n < NN) sum += deg[n];
        }
    }
    s[t] = sum;
    __syncthreads();
    for (int off = 1; off < 1024; off <<= 1) {
        const int x = (t >= off) ? s[t - off] : 0;
        __syncthreads();
        s[t] += x;
        __syncthreads();
    }
    if (t < NBUCK) {
        const int excl = s[t] - sum;
        bucket_base[t] = excl;
        bucket_cursor[t * CURS] = excl;
        if (t == NBUCK - 1) bucket_base[NBUCK] = s[t];
    }
}

// bin edges into bucket regions (packed: src | dstloc<<16)
__global__ __launch_bounds__(256) void k_bin(const int* __restrict__ src,
                                             const int* __restrict__ dst,
                                             int* __restrict__ bucket_cursor,
                                             uint32_t* __restrict__ ebuf) {
    const int e = blockIdx.x * 256 + threadIdx.x;
    if (e < NE) {
        const int d = dst[e];
        const int b = d >> NBSH;
        const int pos = atomicAdd(&bucket_cursor[b * CURS], 1);
        ebuf[pos] = (uint32_t)src[e] | ((uint32_t)(d & 63) << 16);
    }
}

// per-bucket fine fill: LDS cursors, writes confined to ~8KB regions
__global__ __launch_bounds__(256) void k_fillb(const int* __restrict__ deg,
                                               const int* __restrict__ bucket_base,
                                               const uint32_t* __restrict__ ebuf,
                                               int* __restrict__ startv,
                                               unsigned short* __restrict__ esrc) {
    __shared__ int lcur[64];
    const int b = blockIdx.x;
    const int t = threadIdx.x;
    const int bbase = bucket_base[b];
    const int bend  = bucket_base[b + 1];
    if (t < 64) {
        const int node = (b << NBSH) + t;
        const int d    = (node < NN) ? deg[node] : 0;
        int v = d;
#pragma unroll
        for (int off = 1; off < 64; off <<= 1) {
            const int u = __shfl_up(v, off);
            if (t >= off) v += u;
        }
        const int excl = v - d;
        lcur[t] = excl;
        if (node < NN) startv[node] = bbase + excl;
    }
    __syncthreads();
    for (int i = bbase + t; i < bend; i += 256) {
        const uint32_t v = ebuf[i];
        const int dl = (v >> 16) & 63;
        const int p  = atomicAdd(&lcur[dl], 1);
        esrc[bbase + p] = (unsigned short)(v & 0xffffu);
    }
}

// --------------------------------------------------------------- main per-node
// 1 wave per dst node. Lane owns channels (2*lane, 2*lane+1) -> head = lane>>4
// (both channels same head => one weight per lane). Single pass, no max shift.
__global__ __launch_bounds__(256) void k_gat(const uint32_t* __restrict__ zb,
                                             const float4* __restrict__ ssrc,
                                             const float4* __restrict__ sdst,
                                             const int* __restrict__ startv,
                                             const int* __restrict__ deg,
                                             const unsigned short* __restrict__ esrc,
                                             float* __restrict__ out) {
    __shared__ float lw[4][64][4];
    const int ty   = threadIdx.y;
    const int node = blockIdx.x * 4 + ty;
    const int lane = threadIdx.x;
    const int s0   = startv[node];
    const int d    = deg[node];
    const float4 sd = sdst[node];
    const int hsel = lane >> 4;

    float acc0 = 0.f, acc1 = 0.f;
    float dn0 = 0.f, dn1 = 0.f, dn2 = 0.f, dn3 = 0.f;
    for (int base = 0; base < d; base += 64) {
        const int myj = base + lane;
        int sid_l = 0;
        if (myj < d) {
            sid_l = esrc[s0 + myj];
            const float4 ss = ssrc[sid_l];
            const float x0 = __expf(lrelu(ss.x + sd.x));
            const float x1 = __expf(lrelu(ss.y + sd.y));
            const float x2 = __expf(lrelu(ss.z + sd.z));
            const float x3 = __expf(lrelu(ss.w + sd.w));
            dn0 += x0; dn1 += x1; dn2 += x2; dn3 += x3;
            *(float4*)&lw[ty][lane][0] = make_float4(x0, x1, x2, x3);
        }
        const int cnt = min(64, d - base);
#pragma unroll 4
        for (int j = 0; j < cnt; ++j) {
            const int sid = __builtin_amdgcn_readlane(sid_l, j);
            const float w = lw[ty][j][hsel];
            const uint32_t dw = zb[(size_t)sid * 64 + lane];
            const float lo = __builtin_bit_cast(float, dw << 16);
            const float hi = __builtin_bit_cast(float, dw & 0xffff0000u);
            acc0 = fmaf(w, lo, acc0);
            acc1 = fmaf(w, hi, acc1);
        }
    }
#pragma unroll
    for (int off = 32; off > 0; off >>= 1) {
        dn0 += __shfl_xor(dn0, off);
        dn1 += __shfl_xor(dn1, off);
        dn2 += __shfl_xor(dn2, off);
        dn3 += __shfl_xor(dn3, off);
    }
    const float dsel = (hsel == 0) ? dn0 : (hsel == 1) ? dn1 : (hsel == 2) ? dn2 : dn3;
    const float inv  = (dsel > 0.f) ? 1.0f / dsel : 0.f;
    float2 o;
    o.x = acc0 * inv;
    o.y = acc1 * inv;
    *(float2*)&out[(size_t)node * OC + 2 * lane] = o;
}

// ------------------------------------------------------------------- launcher
extern "C" void kernel_launch(void* const* d_in, const int* in_sizes, int n_in,
                              void* d_out, int out_size, void* d_ws, size_t ws_size,
                              hipStream_t stream) {
    const float* h_in = (const float*)d_in[0];
    const float* W    = (const float*)d_in[1];
    const float* a    = (const float*)d_in[2];
    const int*   src  = (const int*)d_in[3];
    const int*   dst  = (const int*)d_in[4];
    float*       out  = (float*)d_out;

    char* w = (char*)d_ws;
    __hip_bfloat16* zb   = (__hip_bfloat16*)(w);              // 12,800,000 B
    float*  ssrc         = (float*)(w + 12800000);            //    800,000 B
    float*  sdst         = (float*)(w + 13600000);            //    800,000 B
    int*    deg          = (int*)(w + 14400000);              //    200,000 B
    int*    startv       = (int*)(w + 14600000);              //    200,000 B
    int*    bucket_base  = (int*)(w + 14800000);              //      4,096 B
    int*    bucket_cur   = (int*)(w + 14804096);              //     50,048 B
    uint32_t* ebuf       = (uint32_t*)(w + 14854400);         //  6,400,000 B
    unsigned short* esrc = (unsigned short*)(w + 21254400);   //  3,200,000 B
    // total ~24.5 MB

    hipMemsetAsync(deg, 0, 200000, stream);

    k_gemm  <<<(NN + 63) / 64, 256, 0, stream>>>(h_in, W, zb);
    k_scores<<<(NN * 4 + 255) / 256, 256, 0, stream>>>((const uint32_t*)zb, a, ssrc, sdst);
    k_hist  <<<(NE + 255) / 256, 256, 0, stream>>>(dst, deg);
    k_bscan <<<1, 1024, 0, stream>>>(deg, bucket_base, bucket_cur);
    k_bin   <<<(NE + 255) / 256, 256, 0, stream>>>(src, dst, bucket_cur, ebuf);
    k_fillb <<<NBUCK, 256, 0, stream>>>(deg, bucket_base, ebuf, startv, esrc);
    k_gat   <<<NN / 4, dim3(64, 4), 0, stream>>>((const uint32_t*)zb,
                                                 (const float4*)ssrc, (const float4*)sdst,
                                                 startv, deg, esrc, out);
}

// Round 6
// 249.410 us; speedup vs baseline: 1.7730x; 1.6773x over previous
//
#include <hip/hip_runtime.h>
#include <hip/hip_bf16.h>
#include <stdint.h>

// GAT v3: 4-edges-per-iteration gather (dwordx4), atomic-light binned CSR build.
// N=50000, E=1.6M, IN=128, OUT=32, H=4 (H*O=128)
// (Resubmission x2: rounds 4-5 died on GPU acquisition, kernel never ran.)

#define NN 50000
#define NE 1600000
#define IN_DIM 128
#define OC 128
#define NBSH 6
#define NBUCK ((NN + 63) >> 6)   // 782 buckets of 64 dst nodes
#define CURS 16                  // bucket cursor stride (ints) = 64 B padding
#define BIN_BLOCKS 256
#define EPB ((NE + BIN_BLOCKS - 1) / BIN_BLOCKS)   // 6250 edges per bin block

__device__ __forceinline__ float lrelu(float x) { return x >= 0.f ? x : 0.01f * x; }

// ---------------------------------------------------------------- projection
// z_bf16 = bf16(h @ Wc^T).  64 nodes x 128 ch tile, k-tiles of 64.
__global__ __launch_bounds__(256) void k_gemm(const float* __restrict__ h,
                                              const float* __restrict__ W,
                                              __hip_bfloat16* __restrict__ zb) {
    __shared__ float hs[64][65];
    __shared__ float ws[64][129];
    const int t  = threadIdx.x;
    const int n0 = blockIdx.x * 64;
    const int tx = t & 31;
    const int ty = t >> 5;

    float acc[8][4];
#pragma unroll
    for (int i = 0; i < 8; ++i)
#pragma unroll
        for (int j = 0; j < 4; ++j) acc[i][j] = 0.f;

    for (int kt = 0; kt < IN_DIM; kt += 64) {
#pragma unroll
        for (int s = 0; s < 4; ++s) {
            const int idx4 = t + s * 256;
            const int n    = idx4 >> 4;
            const int kk   = (idx4 & 15) << 2;
            const int gn   = n0 + n;
            float4 v = make_float4(0.f, 0.f, 0.f, 0.f);
            if (gn < NN) v = *(const float4*)(h + (size_t)gn * IN_DIM + kt + kk);
            hs[kk + 0][n] = v.x; hs[kk + 1][n] = v.y;
            hs[kk + 2][n] = v.z; hs[kk + 3][n] = v.w;
        }
#pragma unroll
        for (int s = 0; s < 8; ++s) {
            const int idx4 = t + s * 256;
            const int c    = idx4 >> 4;
            const int kk   = (idx4 & 15) << 2;
            const float4 v = *(const float4*)(W + (size_t)c * IN_DIM + kt + kk);
            ws[kk + 0][c] = v.x; ws[kk + 1][c] = v.y;
            ws[kk + 2][c] = v.z; ws[kk + 3][c] = v.w;
        }
        __syncthreads();
#pragma unroll 4
        for (int k = 0; k < 64; ++k) {
            float wv[4], hv[8];
#pragma unroll
            for (int j = 0; j < 4; ++j) wv[j] = ws[k][tx + 32 * j];
#pragma unroll
            for (int i = 0; i < 8; ++i) hv[i] = hs[k][ty + 8 * i];
#pragma unroll
            for (int i = 0; i < 8; ++i)
#pragma unroll
                for (int j = 0; j < 4; ++j) acc[i][j] = fmaf(hv[i], wv[j], acc[i][j]);
        }
        __syncthreads();
    }
#pragma unroll
    for (int i = 0; i < 8; ++i) {
        const int gn = n0 + ty + 8 * i;
        if (gn < NN) {
#pragma unroll
            for (int j = 0; j < 4; ++j)
                zb[(size_t)gn * OC + tx + 32 * j] = __float2bfloat16(acc[i][j]);
        }
    }
}

// ------------------------------------------------------------- score tables
__global__ __launch_bounds__(256) void k_scores(const uint32_t* __restrict__ zb32,
                                                const float* __restrict__ a,
                                                float* __restrict__ ssrc,
                                                float* __restrict__ sdst) {
    const int u = blockIdx.x * 256 + threadIdx.x;
    if (u >= NN * 4) return;
    const int n  = u >> 2;
    const int hh = u & 3;
    const uint4* zp = (const uint4*)(zb32 + (size_t)n * 64 + hh * 16);
    const float4* as = (const float4*)(a + hh * 64);
    const float4* ad = as + 8;
    float accs = 0.f, accd = 0.f;
#pragma unroll
    for (int k4 = 0; k4 < 4; ++k4) {
        const uint4 U = zp[k4];
        const float4 a0 = as[2 * k4], a1 = as[2 * k4 + 1];
        const float4 b0 = ad[2 * k4], b1 = ad[2 * k4 + 1];
        float zf[8];
        zf[0] = __builtin_bit_cast(float, U.x << 16);
        zf[1] = __builtin_bit_cast(float, U.x & 0xffff0000u);
        zf[2] = __builtin_bit_cast(float, U.y << 16);
        zf[3] = __builtin_bit_cast(float, U.y & 0xffff0000u);
        zf[4] = __builtin_bit_cast(float, U.z << 16);
        zf[5] = __builtin_bit_cast(float, U.z & 0xffff0000u);
        zf[6] = __builtin_bit_cast(float, U.w << 16);
        zf[7] = __builtin_bit_cast(float, U.w & 0xffff0000u);
        accs += zf[0]*a0.x + zf[1]*a0.y + zf[2]*a0.z + zf[3]*a0.w
              + zf[4]*a1.x + zf[5]*a1.y + zf[6]*a1.z + zf[7]*a1.w;
        accd += zf[0]*b0.x + zf[1]*b0.y + zf[2]*b0.z + zf[3]*b0.w
              + zf[4]*b1.x + zf[5]*b1.y + zf[6]*b1.z + zf[7]*b1.w;
    }
    ssrc[u] = accs;
    sdst[u] = accd;
}

// -------------------------------------------------- bucket histogram (LDS-priv)
__global__ __launch_bounds__(256) void k_bhist(const int* __restrict__ dst,
                                               int* __restrict__ bucket_size) {
    __shared__ int hb[NBUCK];
    const int t = threadIdx.x;
    for (int i = t; i < NBUCK; i += 256) hb[i] = 0;
    __syncthreads();
    for (int e = blockIdx.x * 256 + t; e < NE; e += 128 * 256)
        atomicAdd(&hb[dst[e] >> NBSH], 1);
    __syncthreads();
    for (int i = t; i < NBUCK; i += 256) {
        const int c = hb[i];
        if (c > 0) atomicAdd(&bucket_size[i], c);
    }
}

// ------------------------------------------- bucket scan -> base + global cursor
__global__ __launch_bounds__(1024) void k_bscan(const int* __restrict__ bucket_size,
                                                int* __restrict__ bucket_base,
                                                int* __restrict__ bucket_cursor) {
    __shared__ int s[1024];
    const int t = threadIdx.x;
    const int v0 = (t < NBUCK) ? bucket_size[t] : 0;
    s[t] = v0;
    __syncthreads();
    for (int off = 1; off < 1024; off <<= 1) {
        const int x = (t >= off) ? s[t - off] : 0;
        __syncthreads();
        s[t] += x;
        __syncthreads();
    }
    if (t < NBUCK) {
        const int excl = s[t] - v0;
        bucket_base[t] = excl;
        bucket_cursor[t * CURS] = excl;
        if (t == NBUCK - 1) bucket_base[NBUCK] = s[t];
    }
}

// ------------------- bin edges: LDS count -> per-(block,bucket) reserve -> scatter
__global__ __launch_bounds__(256) void k_bin2(const int* __restrict__ src,
                                              const int* __restrict__ dst,
                                              int* __restrict__ bucket_cursor,
                                              uint32_t* __restrict__ ebuf) {
    __shared__ int hb[NBUCK];
    __shared__ int ofs[NBUCK];
    const int t    = threadIdx.x;
    const int ebeg = blockIdx.x * EPB;
    const int eend = min(ebeg + EPB, NE);
    for (int i = t; i < NBUCK; i += 256) hb[i] = 0;
    __syncthreads();
    for (int e = ebeg + t; e < eend; e += 256)
        atomicAdd(&hb[dst[e] >> NBSH], 1);
    __syncthreads();
    for (int i = t; i < NBUCK; i += 256) {
        const int c = hb[i];
        ofs[i] = (c > 0) ? atomicAdd(&bucket_cursor[i * CURS], c) : 0;
        hb[i] = 0;
    }
    __syncthreads();
    for (int e = ebeg + t; e < eend; e += 256) {
        const int d = dst[e];
        const int b = d >> NBSH;
        const int p = ofs[b] + atomicAdd(&hb[b], 1);
        ebuf[p] = (uint32_t)src[e] | ((uint32_t)(d & 63) << 16);
    }
}

// ------------- per-bucket: deg/startv from LDS count + scan, scatter esrc (ushort)
__global__ __launch_bounds__(256) void k_fillb2(const int* __restrict__ bucket_base,
                                                const uint32_t* __restrict__ ebuf,
                                                int* __restrict__ deg,
                                                int* __restrict__ startv,
                                                unsigned short* __restrict__ esrc) {
    __shared__ int cnt[64];
    __shared__ int cur[64];
    const int b = blockIdx.x;
    const int t = threadIdx.x;
    const int bbase = bucket_base[b];
    const int bend  = bucket_base[b + 1];
    if (t < 64) cnt[t] = 0;
    __syncthreads();
    for (int i = bbase + t; i < bend; i += 256)
        atomicAdd(&cnt[(ebuf[i] >> 16) & 63], 1);
    __syncthreads();
    if (t < 64) {
        const int dcnt = cnt[t];
        int v = dcnt;
#pragma unroll
        for (int off = 1; off < 64; off <<= 1) {
            const int u = __shfl_up(v, off);
            if (t >= off) v += u;
        }
        const int excl = v - dcnt;
        cur[t] = excl;
        const int node = (b << NBSH) + t;
        if (node < NN) {
            deg[node]    = dcnt;
            startv[node] = bbase + excl;
        }
    }
    __syncthreads();
    for (int i = bbase + t; i < bend; i += 256) {
        const uint32_t v = ebuf[i];
        const int dl = (v >> 16) & 63;
        const int p  = atomicAdd(&cur[dl], 1);
        esrc[bbase + p] = (unsigned short)(v & 0xffffu);
    }
}

// --------------------------------------------------------------- main per-node
// 1 wave per dst node. 16-lane group g handles edge 4*it+g; lane16 covers
// channels [8*lane16, 8*lane16+8) of the 128-ch bf16 z row via one dwordx4.
// head of lane16's channels = lane16>>2. {sid, w} pairs staged in LDS.
__global__ __launch_bounds__(256) void k_gat4(const uint32_t* __restrict__ zb,
                                              const float4* __restrict__ ssrc,
                                              const float4* __restrict__ sdst,
                                              const int* __restrict__ startv,
                                              const int* __restrict__ deg,
                                              const unsigned short* __restrict__ esrc,
                                              float* __restrict__ out) {
    __shared__ float2 lp[4][64][4];   // [ty][edge][h] = {sid_bits, w}  (8 KB)
    const int ty     = threadIdx.y;
    const int node   = blockIdx.x * 4 + ty;
    const int lane   = threadIdx.x;
    const int lane16 = lane & 15;
    const int grp    = lane >> 4;
    const int hsel   = lane16 >> 2;
    const int s0     = startv[node];
    const int d      = deg[node];
    const float4 sd  = sdst[node];

    float acc[8];
#pragma unroll
    for (int i = 0; i < 8; ++i) acc[i] = 0.f;
    float dn0 = 0.f, dn1 = 0.f, dn2 = 0.f, dn3 = 0.f;

    for (int base = 0; base < d; base += 64) {
        const int myj = base + lane;
        int sid_l = 0;
        float x0 = 0.f, x1 = 0.f, x2 = 0.f, x3 = 0.f;
        if (myj < d) {
            sid_l = esrc[s0 + myj];
            const float4 ss = ssrc[sid_l];
            x0 = __expf(lrelu(ss.x + sd.x));
            x1 = __expf(lrelu(ss.y + sd.y));
            x2 = __expf(lrelu(ss.z + sd.z));
            x3 = __expf(lrelu(ss.w + sd.w));
            dn0 += x0; dn1 += x1; dn2 += x2; dn3 += x3;
        }
        const float sf = __builtin_bit_cast(float, sid_l);
        float4* lq = (float4*)&lp[ty][lane][0];
        lq[0] = make_float4(sf, x0, sf, x1);
        lq[1] = make_float4(sf, x2, sf, x3);

        const int cnt = min(64, d - base);
        const int nit = (cnt + 3) >> 2;
#pragma unroll 2
        for (int it = 0; it < nit; ++it) {
            const int e4 = (it << 2) + grp;
            const float2 pw = lp[ty][e4][hsel];
            const int   sid = __builtin_bit_cast(int, pw.x);
            const float w   = pw.y;
            const uint4 Z = *(const uint4*)(zb + ((size_t)sid << 6) + (lane16 << 2));
            acc[0] = fmaf(w, __builtin_bit_cast(float, Z.x << 16),          acc[0]);
            acc[1] = fmaf(w, __builtin_bit_cast(float, Z.x & 0xffff0000u),  acc[1]);
            acc[2] = fmaf(w, __builtin_bit_cast(float, Z.y << 16),          acc[2]);
            acc[3] = fmaf(w, __builtin_bit_cast(float, Z.y & 0xffff0000u),  acc[3]);
            acc[4] = fmaf(w, __builtin_bit_cast(float, Z.z << 16),          acc[4]);
            acc[5] = fmaf(w, __builtin_bit_cast(float, Z.z & 0xffff0000u),  acc[5]);
            acc[6] = fmaf(w, __builtin_bit_cast(float, Z.w << 16),          acc[6]);
            acc[7] = fmaf(w, __builtin_bit_cast(float, Z.w & 0xffff0000u),  acc[7]);
        }
    }
    // combine the 4 groups (same channels in lanes l, l^16, l^32, l^48)
#pragma unroll
    for (int i = 0; i < 8; ++i) {
        acc[i] += __shfl_xor(acc[i], 16);
        acc[i] += __shfl_xor(acc[i], 32);
    }
    // denominators (per head, summed over all lanes)
#pragma unroll
    for (int off = 32; off > 0; off >>= 1) {
        dn0 += __shfl_xor(dn0, off);
        dn1 += __shfl_xor(dn1, off);
        dn2 += __shfl_xor(dn2, off);
        dn3 += __shfl_xor(dn3, off);
    }
    const float dsel = (hsel == 0) ? dn0 : (hsel == 1) ? dn1 : (hsel == 2) ? dn2 : dn3;
    const float inv  = (dsel > 0.f) ? 1.0f / dsel : 0.f;
    if (grp == 0) {
        float* op = out + (size_t)node * OC + (lane16 << 3);
        *(float4*)(op)     = make_float4(acc[0]*inv, acc[1]*inv, acc[2]*inv, acc[3]*inv);
        *(float4*)(op + 4) = make_float4(acc[4]*inv, acc[5]*inv, acc[6]*inv, acc[7]*inv);
    }
}

// ------------------------------------------------------------------- launcher
extern "C" void kernel_launch(void* const* d_in, const int* in_sizes, int n_in,
                              void* d_out, int out_size, void* d_ws, size_t ws_size,
                              hipStream_t stream) {
    const float* h_in = (const float*)d_in[0];
    const float* W    = (const float*)d_in[1];
    const float* a    = (const float*)d_in[2];
    const int*   src  = (const int*)d_in[3];
    const int*   dst  = (const int*)d_in[4];
    float*       out  = (float*)d_out;

    char* w = (char*)d_ws;
    __hip_bfloat16* zb   = (__hip_bfloat16*)(w);              // 12,800,000 B
    float*  ssrc         = (float*)(w + 12800000);            //    800,000 B
    float*  sdst         = (float*)(w + 13600000);            //    800,000 B
    int*    deg          = (int*)(w + 14400000);              //    200,000 B
    int*    startv       = (int*)(w + 14600000);              //    200,000 B
    int*    bucket_size  = (int*)(w + 14800000);              //      4,096 B
    int*    bucket_base  = (int*)(w + 14804096);              //      4,096 B
    int*    bucket_cur   = (int*)(w + 14808192);              //     50,048 B
    uint32_t* ebuf       = (uint32_t*)(w + 14858240);         //  6,400,000 B
    unsigned short* esrc = (unsigned short*)(w + 21258240);   //  3,200,000 B
    // total ~24.5 MB

    hipMemsetAsync(bucket_size, 0, 4096, stream);

    k_gemm  <<<(NN + 63) / 64, 256, 0, stream>>>(h_in, W, zb);
    k_scores<<<(NN * 4 + 255) / 256, 256, 0, stream>>>((const uint32_t*)zb, a, ssrc, sdst);
    k_bhist <<<128, 256, 0, stream>>>(dst, bucket_size);
    k_bscan <<<1, 1024, 0, stream>>>(bucket_size, bucket_base, bucket_cur);
    k_bin2  <<<BIN_BLOCKS, 256, 0, stream>>>(src, dst, bucket_cur, ebuf);
    k_fillb2<<<NBUCK, 256, 0, stream>>>(bucket_base, ebuf, deg, startv, esrc);
    k_gat4  <<<NN / 4, dim3(64, 4), 0, stream>>>((const uint32_t*)zb,
                                                 (const float4*)ssrc, (const float4*)sdst,
                                                 startv, deg, esrc, out);
}